// Round 13
// baseline (233.172 us; speedup 1.0000x reference)
//
#include <hip/hip_runtime.h>
#include <hip/hip_bf16.h>

#define SEQ 2048
#define BATCH 4
#define EMBED 768
#define NHEAD 12
#define HDIM 64
#define NROWS (SEQ*BATCH)        // 8192
#define GH (BATCH*NHEAD)         // 48
#define KVBLK 32

typedef __bf16 bf16;
typedef __attribute__((ext_vector_type(4))) __bf16 bf16x4;
typedef __attribute__((ext_vector_type(8))) __bf16 bf16x8;
typedef __attribute__((ext_vector_type(4))) float f32x4;
typedef __attribute__((ext_vector_type(16))) float f32x16;
typedef __attribute__((ext_vector_type(2))) unsigned uint2v;
typedef __attribute__((ext_vector_type(4))) unsigned uint4v;

#define LOG2E 1.44269504088896340736f

// ---------------- fp32 -> bf16 convert (x) ----------------
__global__ __launch_bounds__(256) void cvt_kernel(const float* __restrict__ in,
                                                  bf16* __restrict__ out, int n4) {
  int i = blockIdx.x * 256 + threadIdx.x;
  if (i >= n4) return;
  float4 v = reinterpret_cast<const float4*>(in)[i];
  bf16x4 o;
  o[0] = (bf16)v.x; o[1] = (bf16)v.y; o[2] = (bf16)v.z; o[3] = (bf16)v.w;
  reinterpret_cast<bf16x4*>(out)[i] = o;
}

// ---------------- 4 weight converts in one launch ----------------
__global__ __launch_bounds__(256) void cvt_w4(const float* __restrict__ Wq,
                                              const float* __restrict__ Wk,
                                              const float* __restrict__ Wv,
                                              const float* __restrict__ Wo,
                                              bf16* __restrict__ Wqkvb,
                                              bf16* __restrict__ Wob) {
  const int n4 = EMBED * EMBED / 4;  // 147456
  int i = blockIdx.x * 256 + threadIdx.x;
  if (i >= n4) return;
  const float* src;
  bf16* dst;
  switch (blockIdx.y) {
    case 0: src = Wq; dst = Wqkvb; break;
    case 1: src = Wk; dst = Wqkvb + EMBED * EMBED; break;
    case 2: src = Wv; dst = Wqkvb + 2 * EMBED * EMBED; break;
    default: src = Wo; dst = Wob; break;
  }
  float4 v = reinterpret_cast<const float4*>(src)[i];
  bf16x4 o;
  o[0] = (bf16)v.x; o[1] = (bf16)v.y; o[2] = (bf16)v.z; o[3] = (bf16)v.w;
  reinterpret_cast<bf16x4*>(dst)[i] = o;
}

// ---------------- fused QKV GEMM ----------------
__global__ __launch_bounds__(256) void gemm_qkv(const bf16* __restrict__ A,
                                                const bf16* __restrict__ B,
                                                const float* __restrict__ bq,
                                                const float* __restrict__ bk,
                                                const float* __restrict__ bv,
                                                bf16* __restrict__ Qh,
                                                bf16* __restrict__ Kh,
                                                bf16* __restrict__ Vt) {
  constexpr int K = EMBED;
  __shared__ bf16 As[128 * 32];
  __shared__ bf16 Bs[128 * 32];
  const int tid = threadIdx.x;
  const int l = tid & 63;
  const int w = tid >> 6;
  const int row0 = blockIdx.x * 128;
  const int col0 = blockIdx.y * 128;
  const int wm = (w >> 1) * 64;
  const int wn = (w & 1) * 64;
  const int l15 = l & 15, l4 = l >> 4;

  f32x4 acc[4][4] = {};

  for (int k0 = 0; k0 < K; k0 += 32) {
#pragma unroll
    for (int i = 0; i < 2; ++i) {
      int c = tid + i * 256;
      int r = c >> 2, cc = c & 3;
      __builtin_amdgcn_global_load_lds(
          (const __attribute__((address_space(1))) void*)(A + (size_t)(row0 + r) * K + k0 + cc * 8),
          (__attribute__((address_space(3))) void*)(As + c * 8), 16, 0, 0);
    }
#pragma unroll
    for (int i = 0; i < 2; ++i) {
      int c = tid + i * 256;
      int r = c >> 2, cc = c & 3;
      __builtin_amdgcn_global_load_lds(
          (const __attribute__((address_space(1))) void*)(B + (size_t)(col0 + r) * K + k0 + cc * 8),
          (__attribute__((address_space(3))) void*)(Bs + c * 8), 16, 0, 0);
    }
    __syncthreads();

    bf16x8 af[4], bfr[4];
#pragma unroll
    for (int i = 0; i < 4; ++i)
      af[i] = *reinterpret_cast<const bf16x8*>(&As[(wm + i * 16 + l15) * 32 + l4 * 8]);
#pragma unroll
    for (int j = 0; j < 4; ++j)
      bfr[j] = *reinterpret_cast<const bf16x8*>(&Bs[(wn + j * 16 + l15) * 32 + l4 * 8]);
#pragma unroll
    for (int i = 0; i < 4; ++i)
#pragma unroll
      for (int j = 0; j < 4; ++j)
        acc[i][j] = __builtin_amdgcn_mfma_f32_16x16x32_bf16(af[i], bfr[j], acc[i][j], 0, 0, 0);
    __syncthreads();
  }

  const int sel = blockIdx.y / 6;                       // 0=Q 1=K 2=V (block-uniform)
  const float* bias = sel == 0 ? bq : (sel == 1 ? bk : bv);
  const int colbase = col0 - sel * EMBED;
#pragma unroll
  for (int i = 0; i < 4; ++i) {
#pragma unroll
    for (int j = 0; j < 4; ++j) {
      int col = colbase + wn + j * 16 + l15;
      float bia = bias[col];
#pragma unroll
      for (int r = 0; r < 4; ++r) {
        int row = row0 + wm + i * 16 + l4 * 4 + r;
        float v = acc[i][j][r] + bia;
        int t = row >> 2, bb = row & 3;      // row = t*BATCH + b
        int hh = col >> 6, d = col & 63;     // col = h*64 + d
        int g = bb * NHEAD + hh;             // fairseq head index b*H+h
        if (sel == 0)      Qh[((size_t)g * SEQ + t) * HDIM + d] = (bf16)(v * (0.125f * LOG2E));
        else if (sel == 1) Kh[((size_t)g * SEQ + t) * HDIM + d] = (bf16)v;
        else               Vt[((size_t)g * HDIM + d) * SEQ + t] = (bf16)v;  // transposed
      }
    }
  }
}

// ---------------- out-proj GEMM ----------------
__global__ __launch_bounds__(256) void gemm_out(const bf16* __restrict__ A,
                                                const bf16* __restrict__ B,
                                                const float* __restrict__ bias,
                                                float* __restrict__ outp) {
  constexpr int K = EMBED;
  __shared__ bf16 As[128 * 32];
  __shared__ bf16 Bs[128 * 32];
  const int tid = threadIdx.x;
  const int l = tid & 63;
  const int w = tid >> 6;
  const int row0 = blockIdx.x * 128;
  const int col0 = blockIdx.y * 128;
  const int wm = (w >> 1) * 64;
  const int wn = (w & 1) * 64;
  const int l15 = l & 15, l4 = l >> 4;

  f32x4 acc[4][4] = {};

  for (int k0 = 0; k0 < K; k0 += 32) {
#pragma unroll
    for (int i = 0; i < 2; ++i) {
      int c = tid + i * 256;
      int r = c >> 2, cc = c & 3;
      __builtin_amdgcn_global_load_lds(
          (const __attribute__((address_space(1))) void*)(A + (size_t)(row0 + r) * K + k0 + cc * 8),
          (__attribute__((address_space(3))) void*)(As + c * 8), 16, 0, 0);
    }
#pragma unroll
    for (int i = 0; i < 2; ++i) {
      int c = tid + i * 256;
      int r = c >> 2, cc = c & 3;
      __builtin_amdgcn_global_load_lds(
          (const __attribute__((address_space(1))) void*)(B + (size_t)(col0 + r) * K + k0 + cc * 8),
          (__attribute__((address_space(3))) void*)(Bs + c * 8), 16, 0, 0);
    }
    __syncthreads();

    bf16x8 af[4], bfr[4];
#pragma unroll
    for (int i = 0; i < 4; ++i)
      af[i] = *reinterpret_cast<const bf16x8*>(&As[(wm + i * 16 + l15) * 32 + l4 * 8]);
#pragma unroll
    for (int j = 0; j < 4; ++j)
      bfr[j] = *reinterpret_cast<const bf16x8*>(&Bs[(wn + j * 16 + l15) * 32 + l4 * 8]);
#pragma unroll
    for (int i = 0; i < 4; ++i)
#pragma unroll
      for (int j = 0; j < 4; ++j)
        acc[i][j] = __builtin_amdgcn_mfma_f32_16x16x32_bf16(af[i], bfr[j], acc[i][j], 0, 0, 0);
    __syncthreads();
  }

#pragma unroll
  for (int i = 0; i < 4; ++i) {
#pragma unroll
    for (int j = 0; j < 4; ++j) {
      int col = col0 + wn + j * 16 + l15;
      float bia = bias[col];
#pragma unroll
      for (int r = 0; r < 4; ++r) {
        int row = row0 + wm + i * 16 + l4 * 4 + r;
        outp[(size_t)row * EMBED + col] = acc[i][j][r] + bia;
      }
    }
  }
}

// ---------------- Flash attention: 1-WAVE blocks, zero barriers, counted vmcnt -----
// Block = 1 wave = (head g, 32 q rows). Grid 48*64 = 3072 (12/CU supply).
// LDS 16KB/block (Ks 2x4KB + Vs 2x4KB) -> 10 resident waves/CU, all independent:
// each wave stages ITS OWN K/V tiles (4+4 global_load_lds per step) and orders them
// with s_waitcnt vmcnt(8) -- counts only this wave's loads, so no cross-wave
// visibility hazard (the r10 race class is structurally impossible). No barriers.
// Compute per step = r12's verified 32x32 path: S^T=mfma(K,Q) (col=q=l31,
// row=kv=(reg&3)+8*(reg>>2)+4*l5), in-register P via shfl_xor(32), O^T=mfma(V^T,P^T),
// row sums via ones-A MFMA. Swizzles: K 128B rows chunk^SWZ(r) (8 lanes/chunk,
// bank-balanced, measured 0 conflicts); V 64B rows chunk^(r&3) (8 accesses/bank).
#define SWZ(r) ((((r) & 7) ^ (((r) >> 3) & 3)))
__global__ __launch_bounds__(64, 3) void attn_kernel(const bf16* __restrict__ Qh,
                                                     const bf16* __restrict__ Kh,
                                                     const bf16* __restrict__ Vt,
                                                     bf16* __restrict__ attnb) {
  const int g = blockIdx.x % GH;           // bid%8 == g%8 -> head-affine XCD mapping
  const int q0 = (blockIdx.x / GH) * 32;
  const int l = threadIdx.x;               // 0..63
  const int l31 = l & 31, l5 = l >> 5;
  const int rswk = SWZ(l31);               // K read swizzle (row = l31)
  const int rswv = l31 & 3;                // V read swizzle (row = dt*32+l31 -> &3)

  __shared__ bf16 Ks[2][KVBLK * HDIM];     // 4KB x2: [kv][d], 128B rows
  __shared__ bf16 Vs[2][HDIM * KVBLK];     // 4KB x2: [d][kv], 64B rows

  const bf16* Qp = Qh + (size_t)g * SEQ * HDIM;
  const bf16* Kp = Kh + (size_t)g * SEQ * HDIM;
  const bf16* Vp = Vt + (size_t)g * HDIM * SEQ;

  // K tile: 256 slots of 16B, 4 per lane. slot t: r=t>>3 (kv 0..31), c=t&7.
#define STAGE_K(buf, kv0)                                                               \
  do {                                                                                  \
    _Pragma("unroll") for (int i = 0; i < 4; ++i) {                                     \
      int t = i * 64 + l;                                                               \
      int r_ = t >> 3, c_ = t & 7;                                                      \
      __builtin_amdgcn_global_load_lds(                                                 \
          (const __attribute__((address_space(1))) void*)(Kp + (size_t)((kv0) + r_) * HDIM + ((c_ ^ SWZ(r_)) * 8)), \
          (__attribute__((address_space(3))) void*)(&Ks[buf][t * 8]), 16, 0, 0);        \
    }                                                                                   \
  } while (0)

  // V tile: 256 slots of 16B, 4 per lane. slot t: r=t>>2 (d 0..63), c=t&3.
#define STAGE_V(buf, kv0)                                                               \
  do {                                                                                  \
    _Pragma("unroll") for (int i = 0; i < 4; ++i) {                                     \
      int t = i * 64 + l;                                                               \
      int r_ = t >> 2, c_ = t & 3;                                                      \
      __builtin_amdgcn_global_load_lds(                                                 \
          (const __attribute__((address_space(1))) void*)(Vp + (size_t)r_ * SEQ + (kv0) + ((c_ ^ (r_ & 3)) * 8)), \
          (__attribute__((address_space(3))) void*)(&Vs[buf][t * 8]), 16, 0, 0);        \
    }                                                                                   \
  } while (0)

  // Q B-frags (col=q=l31, k=d=m*16+l5*8+e), loaded from global once: 16 VGPR
  bf16x8 bq[4];
#pragma unroll
  for (int m = 0; m < 4; ++m)
    bq[m] = *reinterpret_cast<const bf16x8*>(
        Qp + (size_t)(q0 + l31) * HDIM + m * 16 + l5 * 8);

  // all-ones A fragment for row-sum MFMA
  bf16x8 vone;
#pragma unroll
  for (int i = 0; i < 8; ++i) vone[i] = (bf16)1.0f;

  f32x16 acco[2] = {};   // O^T tiles: rows d = dt*32 + ...; col = q = l31
  f32x16 accs = {};      // row sums: accs[0] = sum over kv of P[.][q=l31]

  STAGE_K(0, 0);
  STAGE_V(0, 0);

  int cur = 0;
  for (int kv0 = 0; kv0 < SEQ; kv0 += KVBLK) {
    // stage NEXT step's tiles (8 loads); then wait for the 8 older (cur's) only
    int nxt = (kv0 + KVBLK) & (SEQ - 1);
    STAGE_K(cur ^ 1, nxt);
    STAGE_V(cur ^ 1, nxt);
    asm volatile("s_waitcnt vmcnt(8)" ::: "memory");

    // ---- S^T = K Q^T: 4 MFMAs over d=64; A=K[kv=l31][d], B=Q[q][d]
    f32x16 s = {};
#pragma unroll
    for (int m = 0; m < 4; ++m) {
      bf16x8 ak = *reinterpret_cast<const bf16x8*>(
          &Ks[cur][l31 * 64 + (((2 * m + l5) ^ rswk) * 8)]);
      __builtin_amdgcn_s_setprio(1);
      s = __builtin_amdgcn_mfma_f32_32x32x16_bf16(ak, bq[m], s, 0, 0, 0);
      __builtin_amdgcn_s_setprio(0);
    }

    // ---- p = exp2(s), pack quads (reg group gq -> kv quad 8gq+4l5)
    unsigned pg[8];
#pragma unroll
    for (int gq = 0; gq < 4; ++gq) {
      float p0 = exp2f(s[4 * gq + 0]);
      float p1 = exp2f(s[4 * gq + 1]);
      float p2 = exp2f(s[4 * gq + 2]);
      float p3 = exp2f(s[4 * gq + 3]);
      bf16x4 q4;
      q4[0] = (bf16)p0; q4[1] = (bf16)p1; q4[2] = (bf16)p2; q4[3] = (bf16)p3;
      uint2v d2 = __builtin_bit_cast(uint2v, q4);
      pg[2 * gq] = d2[0];
      pg[2 * gq + 1] = d2[1];
    }

    // ---- O^T += V^T P^T per 16-kv chunk j; row sums via ones-A MFMA
#pragma unroll
    for (int j = 0; j < 2; ++j) {
      unsigned sx = l5 ? pg[4 * j + 0] : pg[4 * j + 2];   // quad the partner needs
      unsigned sy = l5 ? pg[4 * j + 1] : pg[4 * j + 3];
      unsigned rx = (unsigned)__shfl_xor((int)sx, 32);
      unsigned ry = (unsigned)__shfl_xor((int)sy, 32);
      unsigned ox = l5 ? pg[4 * j + 2] : pg[4 * j + 0];   // own quad
      unsigned oy = l5 ? pg[4 * j + 3] : pg[4 * j + 1];
      uint4v f;
      f[0] = l5 ? rx : ox;  f[1] = l5 ? ry : oy;          // kv ascending
      f[2] = l5 ? ox : rx;  f[3] = l5 ? oy : ry;
      bf16x8 pb = __builtin_bit_cast(bf16x8, f);
#pragma unroll
      for (int dt = 0; dt < 2; ++dt) {
        bf16x8 av = *reinterpret_cast<const bf16x8*>(
            &Vs[cur][(dt * 32 + l31) * KVBLK + (((2 * j + l5) ^ rswv) * 8)]);
        __builtin_amdgcn_s_setprio(1);
        acco[dt] = __builtin_amdgcn_mfma_f32_32x32x16_bf16(av, pb, acco[dt], 0, 0, 0);
        __builtin_amdgcn_s_setprio(0);
      }
      __builtin_amdgcn_s_setprio(1);
      accs = __builtin_amdgcn_mfma_f32_32x32x16_bf16(vone, pb, accs, 0, 0, 0);
      __builtin_amdgcn_s_setprio(0);
    }
    cur ^= 1;
  }

  // ---- normalize (accs[0] = full row sum for q=l31) and write attnb directly
  const float rinv = __builtin_amdgcn_rcpf(accs[0]);
  const int tq = q0 + l31;
  const int bb = g / NHEAD, hh = g % NHEAD;
  const size_t rowbase = ((size_t)tq * BATCH + bb) * EMBED + hh * HDIM;
#pragma unroll
  for (int dt = 0; dt < 2; ++dt)
#pragma unroll
    for (int gq = 0; gq < 4; ++gq) {
      int d = dt * 32 + 8 * gq + 4 * l5;   // rows (reg&3)+8*gq+4*l5, 4 consecutive
      bf16x4 o4;
      o4[0] = (bf16)(acco[dt][4 * gq + 0] * rinv);
      o4[1] = (bf16)(acco[dt][4 * gq + 1] * rinv);
      o4[2] = (bf16)(acco[dt][4 * gq + 2] * rinv);
      o4[3] = (bf16)(acco[dt][4 * gq + 3] * rinv);
      *reinterpret_cast<bf16x4*>(attnb + rowbase + d) = o4;
    }
}

// ---------------- launch ----------------
extern "C" void kernel_launch(void* const* d_in, const int* in_sizes, int n_in,
                              void* d_out, int out_size, void* d_ws, size_t ws_size,
                              hipStream_t stream) {
  const float* x  = (const float*)d_in[0];
  const float* Wq = (const float*)d_in[1];
  const float* bq = (const float*)d_in[2];
  const float* Wk = (const float*)d_in[3];
  const float* bk = (const float*)d_in[4];
  const float* Wv = (const float*)d_in[5];
  const float* bv = (const float*)d_in[6];
  const float* Wo = (const float*)d_in[7];
  const float* bo = (const float*)d_in[8];
  float* out = (float*)d_out;

  char* ws = (char*)d_ws;
  bf16* xb    = (bf16*)(ws + 0);          // 8192*768*2   = 12582912
  bf16* Wqkvb = (bf16*)(ws + 12582912);   // 2304*768*2   = 3538944
  bf16* Wob   = (bf16*)(ws + 16121856);   // 768*768*2    = 1179648
  bf16* Qh    = (bf16*)(ws + 17301504);   // 48*2048*64*2 = 12582912
  bf16* Kh    = (bf16*)(ws + 29884416);
  bf16* Vt    = (bf16*)(ws + 42467328);
  bf16* attnb = (bf16*)(ws + 55050240);   // 8192*768*2

  cvt_kernel<<<6144, 256, 0, stream>>>(x, xb, NROWS * EMBED / 4);
  cvt_w4<<<dim3(576, 4), 256, 0, stream>>>(Wq, Wk, Wv, Wo, Wqkvb, Wob);

  gemm_qkv<<<dim3(NROWS / 128, 18), 256, 0, stream>>>(xb, Wqkvb, bq, bk, bv, Qh, Kh, Vt);

  attn_kernel<<<GH * (SEQ / 32), 64, 0, stream>>>(Qh, Kh, Vt, attnb);

  gemm_out<<<dim3(NROWS / 128, EMBED / 128), 256, 0, stream>>>(attnb, Wob, bo, out);
}

// Round 14
// 184.172 us; speedup vs baseline: 1.2661x; 1.2661x over previous
//
#include <hip/hip_runtime.h>
#include <hip/hip_bf16.h>

#define SEQ 2048
#define BATCH 4
#define EMBED 768
#define NHEAD 12
#define HDIM 64
#define NROWS (SEQ*BATCH)        // 8192
#define GH (BATCH*NHEAD)         // 48
#define KVBLK 64

typedef __bf16 bf16;
typedef __attribute__((ext_vector_type(4))) __bf16 bf16x4;
typedef __attribute__((ext_vector_type(8))) __bf16 bf16x8;
typedef __attribute__((ext_vector_type(4))) float f32x4;
typedef __attribute__((ext_vector_type(16))) float f32x16;
typedef __attribute__((ext_vector_type(2))) unsigned uint2v;
typedef __attribute__((ext_vector_type(4))) unsigned uint4v;

#define LOG2E 1.44269504088896340736f
#define SWZ(r) ((((r) & 7) ^ (((r) >> 3) & 3)))

// ---------------- fp32 -> bf16 convert (x) ----------------
__global__ __launch_bounds__(256) void cvt_kernel(const float* __restrict__ in,
                                                  bf16* __restrict__ out, int n4) {
  int i = blockIdx.x * 256 + threadIdx.x;
  if (i >= n4) return;
  float4 v = reinterpret_cast<const float4*>(in)[i];
  bf16x4 o;
  o[0] = (bf16)v.x; o[1] = (bf16)v.y; o[2] = (bf16)v.z; o[3] = (bf16)v.w;
  reinterpret_cast<bf16x4*>(out)[i] = o;
}

// ---------------- 4 weight converts in one launch ----------------
__global__ __launch_bounds__(256) void cvt_w4(const float* __restrict__ Wq,
                                              const float* __restrict__ Wk,
                                              const float* __restrict__ Wv,
                                              const float* __restrict__ Wo,
                                              bf16* __restrict__ Wqkvb,
                                              bf16* __restrict__ Wob) {
  const int n4 = EMBED * EMBED / 4;  // 147456
  int i = blockIdx.x * 256 + threadIdx.x;
  if (i >= n4) return;
  const float* src;
  bf16* dst;
  switch (blockIdx.y) {
    case 0: src = Wq; dst = Wqkvb; break;
    case 1: src = Wk; dst = Wqkvb + EMBED * EMBED; break;
    case 2: src = Wv; dst = Wqkvb + 2 * EMBED * EMBED; break;
    default: src = Wo; dst = Wob; break;
  }
  float4 v = reinterpret_cast<const float4*>(src)[i];
  bf16x4 o;
  o[0] = (bf16)v.x; o[1] = (bf16)v.y; o[2] = (bf16)v.z; o[3] = (bf16)v.w;
  reinterpret_cast<bf16x4*>(dst)[i] = o;
}

// ---------------- fused QKV GEMM: BK=64, swizzled [128][64] tiles ------------------
// 12 K-iters (vs 24 at BK=32) -> half the barrier drains. Tiles staged with
// pre-swizzled global source (chunk ^ SWZ(row)), read back with the same XOR:
// bank = chunk'*4 (row*128B drops mod 32 banks), chunk' spans 8 values over the
// 16 rows a frag-read touches -> 2-way max (free). Same epilogue as before.
__global__ __launch_bounds__(256) void gemm_qkv(const bf16* __restrict__ A,
                                                const bf16* __restrict__ B,
                                                const float* __restrict__ bq,
                                                const float* __restrict__ bk,
                                                const float* __restrict__ bv,
                                                bf16* __restrict__ Qh,
                                                bf16* __restrict__ Kh,
                                                bf16* __restrict__ Vt) {
  constexpr int K = EMBED;
  __shared__ bf16 As[128 * 64];   // 16KB
  __shared__ bf16 Bs[128 * 64];   // 16KB
  const int tid = threadIdx.x;
  const int l = tid & 63;
  const int w = tid >> 6;
  const int row0 = blockIdx.x * 128;
  const int col0 = blockIdx.y * 128;
  const int wm = (w >> 1) * 64;
  const int wn = (w & 1) * 64;
  const int l15 = l & 15, l4 = l >> 4;

  f32x4 acc[4][4] = {};

  for (int k0 = 0; k0 < K; k0 += 64) {
#pragma unroll
    for (int i = 0; i < 4; ++i) {
      int t = i * 256 + tid;
      int r = t >> 3, c = t & 7;
      __builtin_amdgcn_global_load_lds(
          (const __attribute__((address_space(1))) void*)(A + (size_t)(row0 + r) * K + k0 + ((c ^ SWZ(r)) * 8)),
          (__attribute__((address_space(3))) void*)(As + t * 8), 16, 0, 0);
    }
#pragma unroll
    for (int i = 0; i < 4; ++i) {
      int t = i * 256 + tid;
      int r = t >> 3, c = t & 7;
      __builtin_amdgcn_global_load_lds(
          (const __attribute__((address_space(1))) void*)(B + (size_t)(col0 + r) * K + k0 + ((c ^ SWZ(r)) * 8)),
          (__attribute__((address_space(3))) void*)(Bs + t * 8), 16, 0, 0);
    }
    __syncthreads();

#pragma unroll
    for (int ks = 0; ks < 2; ++ks) {
      bf16x8 af[4], bfr[4];
#pragma unroll
      for (int i = 0; i < 4; ++i) {
        int row = wm + i * 16 + l15;
        af[i] = *reinterpret_cast<const bf16x8*>(&As[row * 64 + (((ks * 4 + l4) ^ SWZ(row)) * 8)]);
      }
#pragma unroll
      for (int j = 0; j < 4; ++j) {
        int row = wn + j * 16 + l15;
        bfr[j] = *reinterpret_cast<const bf16x8*>(&Bs[row * 64 + (((ks * 4 + l4) ^ SWZ(row)) * 8)]);
      }
#pragma unroll
      for (int i = 0; i < 4; ++i)
#pragma unroll
        for (int j = 0; j < 4; ++j)
          acc[i][j] = __builtin_amdgcn_mfma_f32_16x16x32_bf16(af[i], bfr[j], acc[i][j], 0, 0, 0);
    }
    __syncthreads();
  }

  const int sel = blockIdx.y / 6;                       // 0=Q 1=K 2=V (block-uniform)
  const float* bias = sel == 0 ? bq : (sel == 1 ? bk : bv);
  const int colbase = col0 - sel * EMBED;
#pragma unroll
  for (int i = 0; i < 4; ++i) {
#pragma unroll
    for (int j = 0; j < 4; ++j) {
      int col = colbase + wn + j * 16 + l15;
      float bia = bias[col];
#pragma unroll
      for (int r = 0; r < 4; ++r) {
        int row = row0 + wm + i * 16 + l4 * 4 + r;
        float v = acc[i][j][r] + bia;
        int t = row >> 2, bb = row & 3;      // row = t*BATCH + b
        int hh = col >> 6, d = col & 63;     // col = h*64 + d
        int g = bb * NHEAD + hh;             // fairseq head index b*H+h
        if (sel == 0)      Qh[((size_t)g * SEQ + t) * HDIM + d] = (bf16)(v * (0.125f * LOG2E));
        else if (sel == 1) Kh[((size_t)g * SEQ + t) * HDIM + d] = (bf16)v;
        else               Vt[((size_t)g * HDIM + d) * SEQ + t] = (bf16)v;  // transposed
      }
    }
  }
}

// ---------------- out-proj GEMM: BK=64, swizzled (same structure) ------------------
__global__ __launch_bounds__(256) void gemm_out(const bf16* __restrict__ A,
                                                const bf16* __restrict__ B,
                                                const float* __restrict__ bias,
                                                float* __restrict__ outp) {
  constexpr int K = EMBED;
  __shared__ bf16 As[128 * 64];
  __shared__ bf16 Bs[128 * 64];
  const int tid = threadIdx.x;
  const int l = tid & 63;
  const int w = tid >> 6;
  const int row0 = blockIdx.x * 128;
  const int col0 = blockIdx.y * 128;
  const int wm = (w >> 1) * 64;
  const int wn = (w & 1) * 64;
  const int l15 = l & 15, l4 = l >> 4;

  f32x4 acc[4][4] = {};

  for (int k0 = 0; k0 < K; k0 += 64) {
#pragma unroll
    for (int i = 0; i < 4; ++i) {
      int t = i * 256 + tid;
      int r = t >> 3, c = t & 7;
      __builtin_amdgcn_global_load_lds(
          (const __attribute__((address_space(1))) void*)(A + (size_t)(row0 + r) * K + k0 + ((c ^ SWZ(r)) * 8)),
          (__attribute__((address_space(3))) void*)(As + t * 8), 16, 0, 0);
    }
#pragma unroll
    for (int i = 0; i < 4; ++i) {
      int t = i * 256 + tid;
      int r = t >> 3, c = t & 7;
      __builtin_amdgcn_global_load_lds(
          (const __attribute__((address_space(1))) void*)(B + (size_t)(col0 + r) * K + k0 + ((c ^ SWZ(r)) * 8)),
          (__attribute__((address_space(3))) void*)(Bs + t * 8), 16, 0, 0);
    }
    __syncthreads();

#pragma unroll
    for (int ks = 0; ks < 2; ++ks) {
      bf16x8 af[4], bfr[4];
#pragma unroll
      for (int i = 0; i < 4; ++i) {
        int row = wm + i * 16 + l15;
        af[i] = *reinterpret_cast<const bf16x8*>(&As[row * 64 + (((ks * 4 + l4) ^ SWZ(row)) * 8)]);
      }
#pragma unroll
      for (int j = 0; j < 4; ++j) {
        int row = wn + j * 16 + l15;
        bfr[j] = *reinterpret_cast<const bf16x8*>(&Bs[row * 64 + (((ks * 4 + l4) ^ SWZ(row)) * 8)]);
      }
#pragma unroll
      for (int i = 0; i < 4; ++i)
#pragma unroll
        for (int j = 0; j < 4; ++j)
          acc[i][j] = __builtin_amdgcn_mfma_f32_16x16x32_bf16(af[i], bfr[j], acc[i][j], 0, 0, 0);
    }
    __syncthreads();
  }

#pragma unroll
  for (int i = 0; i < 4; ++i) {
#pragma unroll
    for (int j = 0; j < 4; ++j) {
      int col = col0 + wn + j * 16 + l15;
      float bia = bias[col];
#pragma unroll
      for (int r = 0; r < 4; ++r) {
        int row = row0 + wm + i * 16 + l4 * 4 + r;
        outp[(size_t)row * EMBED + col] = acc[i][j][r] + bia;
      }
    }
  }
}

// ---------------- Flash attention: r12 kernel (unchanged, proven) ------------------
__global__ __launch_bounds__(256, 4) void attn_kernel(const bf16* __restrict__ Qh,
                                                      const bf16* __restrict__ Kh,
                                                      const bf16* __restrict__ Vt,
                                                      bf16* __restrict__ attnb) {
  const int g = blockIdx.x % GH;
  const int q0 = (blockIdx.x / GH) * 128;
  const int tid = threadIdx.x;
  const int w = tid >> 6, l = tid & 63;
  const int l31 = l & 31, l5 = l >> 5;
  const int qw = q0 + w * 32;
  const int rsw = SWZ(l31);              // lane-side read swizzle (h/dt-independent)

  __shared__ bf16 Ks[2][KVBLK * HDIM];   // 8KB x2: [kv][d]
  __shared__ bf16 Vs[2][HDIM * KVBLK];   // 8KB x2: [d][kv]

  const bf16* Qp = Qh + (size_t)g * SEQ * HDIM;
  const bf16* Kp = Kh + (size_t)g * SEQ * HDIM;
  const bf16* Vp = Vt + (size_t)g * HDIM * SEQ;

#define STAGE_K(buf, kv0)                                                               \
  do {                                                                                  \
    _Pragma("unroll") for (int i = 0; i < 2; ++i) {                                     \
      int t = i * 256 + tid;                                                            \
      int r_ = t >> 3, c_ = t & 7;                                                      \
      __builtin_amdgcn_global_load_lds(                                                 \
          (const __attribute__((address_space(1))) void*)(Kp + (size_t)((kv0) + r_) * HDIM + ((c_ ^ SWZ(r_)) * 8)), \
          (__attribute__((address_space(3))) void*)(&Ks[buf][t * 8]), 16, 0, 0);        \
    }                                                                                   \
  } while (0)

#define STAGE_V(buf, kv0)                                                               \
  do {                                                                                  \
    _Pragma("unroll") for (int i = 0; i < 2; ++i) {                                     \
      int t = i * 256 + tid;                                                            \
      int r_ = t >> 3, c_ = t & 7;                                                      \
      __builtin_amdgcn_global_load_lds(                                                 \
          (const __attribute__((address_space(1))) void*)(Vp + (size_t)r_ * SEQ + (kv0) + ((c_ ^ SWZ(r_)) * 8)), \
          (__attribute__((address_space(3))) void*)(&Vs[buf][t * 8]), 16, 0, 0);        \
    }                                                                                   \
  } while (0)

  // Q B-frags (col=q=l31, k=d=m*16+l5*8+j), from global once: 16 VGPR
  bf16x8 bq[4];
#pragma unroll
  for (int m = 0; m < 4; ++m)
    bq[m] = *reinterpret_cast<const bf16x8*>(
        Qp + (size_t)(qw + l31) * HDIM + m * 16 + l5 * 8);

  // all-ones A fragment for row-sum MFMA
  bf16x8 vone;
#pragma unroll
  for (int i = 0; i < 8; ++i) vone[i] = (bf16)1.0f;

  f32x16 acco[2] = {};   // O^T tiles: rows d = dt*32 + ...; col = q = l31
  f32x16 accs = {};      // row sums: every element = sum over kv of P[.][q=l31]

  STAGE_K(0, 0);
  STAGE_V(0, 0);
  __syncthreads();

  int cur = 0;
  for (int kv0 = 0; kv0 < SEQ; kv0 += KVBLK) {
    // stage NEXT step's K and V (wrapped on last iter; consumed next step)
    int nxt = (kv0 + KVBLK) & (SEQ - 1);
    STAGE_V(cur ^ 1, nxt);
    STAGE_K(cur ^ 1, nxt);

#pragma unroll
    for (int h = 0; h < 2; ++h) {                   // two 32-kv halves
      // ---- S^T = K Q^T: 4 MFMAs over d; A=K[kv=32h+l31][d], B=Q[q][d]
      f32x16 s = {};
#pragma unroll
      for (int m = 0; m < 4; ++m) {
        bf16x8 ak = *reinterpret_cast<const bf16x8*>(
            &Ks[cur][(32 * h + l31) * 64 + (((2 * m + l5) ^ rsw) * 8)]);
        __builtin_amdgcn_s_setprio(1);
        s = __builtin_amdgcn_mfma_f32_32x32x16_bf16(ak, bq[m], s, 0, 0, 0);
        __builtin_amdgcn_s_setprio(0);
      }

      // ---- p = exp2(s), pack quads (reg group gq -> kv quad 2gq+l5)
      unsigned pg[8];
#pragma unroll
      for (int gq = 0; gq < 4; ++gq) {
        float p0 = exp2f(s[4 * gq + 0]);
        float p1 = exp2f(s[4 * gq + 1]);
        float p2 = exp2f(s[4 * gq + 2]);
        float p3 = exp2f(s[4 * gq + 3]);
        bf16x4 q4;
        q4[0] = (bf16)p0; q4[1] = (bf16)p1; q4[2] = (bf16)p2; q4[3] = (bf16)p3;
        uint2v d2 = __builtin_bit_cast(uint2v, q4);
        pg[2 * gq] = d2[0];
        pg[2 * gq + 1] = d2[1];
      }

      // ---- O^T += V^T P^T; row sums via ones-A MFMA on the same B-frag
#pragma unroll
      for (int j = 0; j < 2; ++j) {
        unsigned sx = l5 ? pg[4 * j + 0] : pg[4 * j + 2];   // quad the partner needs
        unsigned sy = l5 ? pg[4 * j + 1] : pg[4 * j + 3];
        unsigned rx = (unsigned)__shfl_xor((int)sx, 32);
        unsigned ry = (unsigned)__shfl_xor((int)sy, 32);
        unsigned ox = l5 ? pg[4 * j + 2] : pg[4 * j + 0];   // own quad
        unsigned oy = l5 ? pg[4 * j + 3] : pg[4 * j + 1];
        uint4v f;
        f[0] = l5 ? rx : ox;  f[1] = l5 ? ry : oy;          // kv ascending
        f[2] = l5 ? ox : rx;  f[3] = l5 ? oy : ry;
        bf16x8 pb = __builtin_bit_cast(bf16x8, f);
#pragma unroll
        for (int dt = 0; dt < 2; ++dt) {
          bf16x8 av = *reinterpret_cast<const bf16x8*>(
              &Vs[cur][(dt * 32 + l31) * 64 + (((4 * h + 2 * j + l5) ^ rsw) * 8)]);
          __builtin_amdgcn_s_setprio(1);
          acco[dt] = __builtin_amdgcn_mfma_f32_32x32x16_bf16(av, pb, acco[dt], 0, 0, 0);
          __builtin_amdgcn_s_setprio(0);
        }
        __builtin_amdgcn_s_setprio(1);
        accs = __builtin_amdgcn_mfma_f32_32x32x16_bf16(vone, pb, accs, 0, 0, 0);
        __builtin_amdgcn_s_setprio(0);
      }
    }
    __syncthreads();   // drains all staging loads; next step reads cur^1 safely
    cur ^= 1;
  }

  // ---- normalize (accs[0] = full row sum for q=l31) and write attnb directly
  const float rinv = __builtin_amdgcn_rcpf(accs[0]);
  const int tq = qw + l31;
  const int bb = g / NHEAD, hh = g % NHEAD;
  const size_t rowbase = ((size_t)tq * BATCH + bb) * EMBED + hh * HDIM;
#pragma unroll
  for (int dt = 0; dt < 2; ++dt)
#pragma unroll
    for (int gq = 0; gq < 4; ++gq) {
      int d = dt * 32 + 8 * gq + 4 * l5;   // rows (reg&3)+8*gq+4*l5, 4 consecutive
      bf16x4 o4;
      o4[0] = (bf16)(acco[dt][4 * gq + 0] * rinv);
      o4[1] = (bf16)(acco[dt][4 * gq + 1] * rinv);
      o4[2] = (bf16)(acco[dt][4 * gq + 2] * rinv);
      o4[3] = (bf16)(acco[dt][4 * gq + 3] * rinv);
      *reinterpret_cast<bf16x4*>(attnb + rowbase + d) = o4;
    }
}

// ---------------- launch ----------------
extern "C" void kernel_launch(void* const* d_in, const int* in_sizes, int n_in,
                              void* d_out, int out_size, void* d_ws, size_t ws_size,
                              hipStream_t stream) {
  const float* x  = (const float*)d_in[0];
  const float* Wq = (const float*)d_in[1];
  const float* bq = (const float*)d_in[2];
  const float* Wk = (const float*)d_in[3];
  const float* bk = (const float*)d_in[4];
  const float* Wv = (const float*)d_in[5];
  const float* bv = (const float*)d_in[6];
  const float* Wo = (const float*)d_in[7];
  const float* bo = (const float*)d_in[8];
  float* out = (float*)d_out;

  char* ws = (char*)d_ws;
  bf16* xb    = (bf16*)(ws + 0);          // 8192*768*2   = 12582912
  bf16* Wqkvb = (bf16*)(ws + 12582912);   // 2304*768*2   = 3538944
  bf16* Wob   = (bf16*)(ws + 16121856);   // 768*768*2    = 1179648
  bf16* Qh    = (bf16*)(ws + 17301504);   // 48*2048*64*2 = 12582912
  bf16* Kh    = (bf16*)(ws + 29884416);
  bf16* Vt    = (bf16*)(ws + 42467328);
  bf16* attnb = (bf16*)(ws + 55050240);   // 8192*768*2

  cvt_kernel<<<6144, 256, 0, stream>>>(x, xb, NROWS * EMBED / 4);
  cvt_w4<<<dim3(576, 4), 256, 0, stream>>>(Wq, Wk, Wv, Wo, Wqkvb, Wob);

  gemm_qkv<<<dim3(NROWS / 128, 18), 256, 0, stream>>>(xb, Wqkvb, bq, bk, bv, Qh, Kh, Vt);

  attn_kernel<<<GH * (SEQ / 128), 256, 0, stream>>>(Qh, Kh, Vt, attnb);

  gemm_out<<<dim3(NROWS / 128, EMBED / 128), 256, 0, stream>>>(attnb, Wob, bo, out);
}